// Round 8
// baseline (309.237 us; speedup 1.0000x reference)
//
#include <hip/hip_runtime.h>
#include <hip/hip_bf16.h>

// WindowAttention (Swin) split pipeline for MI355X:
//   K1 qkv:  per-window GEMM (roll fused on load)  -> Qg/Kg [bw][49][192], VTg [bw][192][64]
//   K2 attn: per-(window,head), zero-LDS, zero-barrier, lane-local softmax -> O2 [bw][49][192]
//   K3 proj: per-window GEMM, inverse roll on store -> out
// bf16 MFMA, f32 accum. Fragment layout (gfx950, verified r2-r6):
//   A (16x32): lane l holds A[l&15][8*(l>>4)+j]   B (32x16): lane l holds B[8*(l>>4)+j][l&15]
//   C/D: lane l reg r -> C[4*(l>>4)+r][l&15]

typedef __bf16 bf16x8 __attribute__((ext_vector_type(8)));
typedef __bf16 bf16x4 __attribute__((ext_vector_type(4)));
typedef float f32x4 __attribute__((ext_vector_type(4)));
using bf = __bf16;

#define MFMA16(a, b, c) __builtin_amdgcn_mfma_f32_16x16x32_bf16((a), (b), (c), 0, 0, 0)

static constexpr float kNEG = -1000000000.0f;
static constexpr float kScale = 0.17677669529663687f;  // 32^-0.5

// workspace layout (bytes)
static constexpr size_t OFF_WQKVT = 0;                      // bf16 [576][192]
static constexpr size_t OFF_WOUTT = 221184;                 // bf16 [192][192]
static constexpr size_t OFF_TBLBF = 294912;                 // bf16 [4][49][68]
static constexpr size_t OFF_QG    = 321568;                 // bf16 [2048][49][192]
static constexpr size_t OFF_KG    = OFF_QG + 38535168ull;   // bf16 [2048][49][192]
static constexpr size_t OFF_VT    = OFF_KG + 38535168ull;   // bf16 [2048][192][64]
static constexpr size_t OFF_O2    = OFF_VT + 50331648ull;   // bf16 [2048][49][192]

static constexpr int VT_STR   = 64;    // V^T row stride: t up to 63 must fit (r7 bug: 52 overflowed)
static constexpr int X_STRIDE = 200;   // K1 LDS x-window stride
static constexpr int O_STRIDE = 200;   // K3 LDS O stride

__device__ __forceinline__ unsigned pack2(float a, float b) {
  union { bf h[2]; unsigned u; } cv;
  cv.h[0] = (bf)a; cv.h[1] = (bf)b;
  return cv.u;
}

// ---------------- kernel 0: weight transposes + bf16 bias/mask tables ----------------
__global__ void prep_kernel(const float* __restrict__ wqkv, const float* __restrict__ wout,
                            const float* __restrict__ pos, char* __restrict__ ws) {
  bf* wqkvT = (bf*)(ws + OFF_WQKVT);
  bf* woutT = (bf*)(ws + OFF_WOUTT);
  bf* tblbf = (bf*)(ws + OFF_TBLBF);
  int tid = blockIdx.x * blockDim.x + threadIdx.x;
  int nthr = gridDim.x * blockDim.x;
  for (int i = tid; i < 192 * 576; i += nthr) {
    int k = i / 576, n = i % 576;
    wqkvT[n * 192 + k] = (bf)wqkv[i];
  }
  for (int i = tid; i < 192 * 192; i += nthr) {
    int k = i / 192, n = i % 192;
    woutT[n * 192 + k] = (bf)wout[i];
  }
  for (int i = tid; i < 4 * 49 * 68; i += nthr) {
    int type = i / (49 * 68), rem = i % (49 * 68), r = rem / 68, c = rem % 68;
    float v = 0.0f;
    if (c < 64) {
      if (c < 49) {
        int ix = r / 7, iy = r % 7, jx = c / 7, jy = c % 7;
        v = pos[(jx - ix + 6) * 13 + (jy - iy + 6)];
        if ((type & 1) && ((r >= 28) != (c >= 28))) v += kNEG;  // ul mask
        if ((type & 2) && ((iy >= 4) != (jy >= 4))) v += kNEG;  // lr mask
      } else {
        v = kNEG;  // pad cols -> P==0
      }
    }
    tblbf[i] = (bf)v;
  }
}

// ---------------- K1: QKV GEMM, 1 block = 1 window, 512 thr (8 waves) ----------------
__global__ __launch_bounds__(512, 6) void qkv_kernel(const float* __restrict__ x,
                                                     char* __restrict__ ws) {
  __shared__ __align__(16) bf Xl[49 * X_STRIDE];  // 19600 B

  const bf* wqkvT = (const bf*)(ws + OFF_WQKVT);
  bf* Qg = (bf*)(ws + OFF_QG);
  bf* Kg = (bf*)(ws + OFF_KG);
  bf* VT = (bf*)(ws + OFF_VT);

  int bw = blockIdx.x;
  int b = bw >> 6, win = bw & 63;
  int wh = win >> 3, wwi = win & 7;

  int tid = threadIdx.x;
  int wave = tid >> 6, lane = tid & 63;
  int l15 = lane & 15, g = lane >> 4;
  int mrow = wave >> 2, ncol = wave & 3;

  // stage x window (roll fused) -> LDS bf16
#pragma unroll
  for (int it = 0; it < 3; ++it) {
    int chunk = it * 512 + tid;  // 49 rows * 24 chunks of 8
    if (chunk < 1176) {
      int r = chunk / 24, c8 = (chunk % 24) * 8;
      int tr = r / 7, tc = r % 7;
      int h = wh * 7 + tr + 3; if (h >= 56) h -= 56;
      int w = wwi * 7 + tc + 3; if (w >= 56) w -= 56;
      const float* p = x + (((size_t)b * 56 + h) * 56 + w) * 192 + c8;
      bf16x8 v;
#pragma unroll
      for (int j = 0; j < 8; ++j) v[j] = (bf)p[j];
      *(bf16x8*)(Xl + r * X_STRIDE + c8) = v;
    }
  }
  __syncthreads();

  // pass A: K,V columns [192 + 96*ncol, +96), rows [32*mrow, +32)
  {
    f32x4 acc[2][6] = {};
#pragma unroll
    for (int ks = 0; ks < 6; ++ks) {
      bf16x8 a[2];
#pragma unroll
      for (int mt = 0; mt < 2; ++mt) {
        int t = mrow * 32 + mt * 16 + l15; if (t > 48) t = 48;  // dup; handled downstream
        a[mt] = *(const bf16x8*)(Xl + t * X_STRIDE + ks * 32 + g * 8);
      }
#pragma unroll
      for (int nt = 0; nt < 6; ++nt) {
        int n = 192 + ncol * 96 + nt * 16 + l15;
        bf16x8 bfr = *(const bf16x8*)(wqkvT + (size_t)n * 192 + ks * 32 + g * 8);
#pragma unroll
        for (int mt = 0; mt < 2; ++mt) acc[mt][nt] = MFMA16(a[mt], bfr, acc[mt][nt]);
      }
    }
#pragma unroll
    for (int nt = 0; nt < 6; ++nt) {
      int n = 192 + ncol * 96 + nt * 16 + l15;
      int s3 = n / 192;           // 1 = K, 2 = V
      int c = n - s3 * 192;       // 0..191 = head*32 + d
#pragma unroll
      for (int mt = 0; mt < 2; ++mt) {
        if (s3 == 1) {
#pragma unroll
          for (int r = 0; r < 4; ++r) {
            int t = mrow * 32 + mt * 16 + 4 * g + r;
            if (t < 49) Kg[((size_t)bw * 49 + t) * 192 + c] = (bf)acc[mt][nt][r];
          }
        } else {
          // V^T packed: [bw][c][64], 4 consecutive t per lane (t 49..63 dups killed by P==0)
          int tb4 = mrow * 32 + mt * 16 + 4 * g;
          union { unsigned u[2]; } pk;
          pk.u[0] = pack2(acc[mt][nt][0], acc[mt][nt][1]);
          pk.u[1] = pack2(acc[mt][nt][2], acc[mt][nt][3]);
          *(uint2*)(VT + ((size_t)bw * 192 + c) * VT_STR + tb4) = *(uint2*)pk.u;
        }
      }
    }
  }

  // pass B: Q columns [48*ncol, +48)
  {
    f32x4 qacc[2][3] = {};
#pragma unroll
    for (int ks = 0; ks < 6; ++ks) {
      bf16x8 a[2];
#pragma unroll
      for (int mt = 0; mt < 2; ++mt) {
        int t = mrow * 32 + mt * 16 + l15; if (t > 48) t = 48;
        a[mt] = *(const bf16x8*)(Xl + t * X_STRIDE + ks * 32 + g * 8);
      }
#pragma unroll
      for (int nt = 0; nt < 3; ++nt) {
        int n = ncol * 48 + nt * 16 + l15;
        bf16x8 bfr = *(const bf16x8*)(wqkvT + (size_t)n * 192 + ks * 32 + g * 8);
#pragma unroll
        for (int mt = 0; mt < 2; ++mt) qacc[mt][nt] = MFMA16(a[mt], bfr, qacc[mt][nt]);
      }
    }
#pragma unroll
    for (int nt = 0; nt < 3; ++nt) {
      int n = ncol * 48 + nt * 16 + l15;
#pragma unroll
      for (int mt = 0; mt < 2; ++mt) {
#pragma unroll
        for (int r = 0; r < 4; ++r) {
          int t = mrow * 32 + mt * 16 + 4 * g + r;
          if (t < 49) Qg[((size_t)bw * 49 + t) * 192 + n] = (bf)qacc[mt][nt][r];
        }
      }
    }
  }
}

// ---------------- K2: attention, 1 block = 1 (window, head), 128 thr, no LDS ----------------
__global__ __launch_bounds__(128, 6) void attn_kernel(const char* __restrict__ ws) {
  int id = blockIdx.x;
  int bw = id / 6, head = id - bw * 6;
  int win = bw & 63;
  int wh = win >> 3, wwi = win & 7;
  int type = ((wh == 7) ? 1 : 0) | ((wwi == 7) ? 2 : 0);

  const bf* Qh = (const bf*)(ws + OFF_QG) + (size_t)bw * 49 * 192 + head * 32;
  const bf* Kh = (const bf*)(ws + OFF_KG) + (size_t)bw * 49 * 192 + head * 32;
  const bf* Vh = (const bf*)(ws + OFF_VT) + ((size_t)bw * 192 + head * 32) * VT_STR;
  const bf* Tb = (const bf*)(ws + OFF_TBLBF) + type * 49 * 68;
  bf* O2 = (bf*)(ws + OFF_O2) + (size_t)bw * 49 * 192 + head * 32;

  int tid = threadIdx.x;
  int wave = tid >> 6, lane = tid & 63;
  int l15 = lane & 15, g = lane >> 4;

  unsigned pp[2][4][2];
#pragma unroll
  for (int ii = 0; ii < 2; ++ii) {
    int mq = wave * 2 + ii;
    int q = mq * 16 + l15;
    int qc = q > 48 ? 48 : q;
    bf16x8 qf = *(const bf16x8*)(Qh + (size_t)qc * 192 + g * 8);  // B-frag Q[q][d]

    f32x4 sa[4];
#pragma unroll
    for (int T = 0; T < 4; ++T) {
      int kt = ((l15 >> 2) << 3) + ((T & 1) << 2) + ((T >> 1) << 5) + (l15 & 3);
      int ktc = kt > 48 ? 48 : kt;  // dup; killed by NEG bias col
      bf16x8 kf = *(const bf16x8*)(Kh + (size_t)ktc * 192 + g * 8);  // A-frag K[kt][d]
      f32x4 z = {};
      sa[T] = MFMA16(kf, qf, z);
    }

    float e[4][4];
    float lsum = 0.0f;
#pragma unroll
    for (int T = 0; T < 4; ++T) {
      int cb = (g << 3) + ((T & 1) << 2) + ((T >> 1) << 5);
      bf16x4 bias = *(const bf16x4*)(Tb + qc * 68 + cb);
#pragma unroll
      for (int r = 0; r < 4; ++r) {
        float ev = __expf(sa[T][r] * kScale + (float)bias[r]);
        e[T][r] = ev;
        lsum += ev;
      }
    }
    lsum += __shfl_xor(lsum, 16);
    lsum += __shfl_xor(lsum, 32);
    float rinv = 1.0f / lsum;
#pragma unroll
    for (int T = 0; T < 4; ++T) {
      pp[ii][T][0] = pack2(e[T][0] * rinv, e[T][1] * rinv);
      pp[ii][T][1] = pack2(e[T][2] * rinv, e[T][3] * rinv);
    }
  }

  // O = P V : A-frags from pp regs, B-frags from V^T global
#pragma unroll
  for (int ii = 0; ii < 2; ++ii) {
    int mq = wave * 2 + ii;
    f32x4 o0 = {}, o1 = {};
#pragma unroll
    for (int ks = 0; ks < 2; ++ks) {
      union { unsigned u[4]; bf16x8 v; } af;
      af.u[0] = pp[ii][2 * ks][0];
      af.u[1] = pp[ii][2 * ks][1];
      af.u[2] = pp[ii][2 * ks + 1][0];
      af.u[3] = pp[ii][2 * ks + 1][1];
      bf16x8 v0 = *(const bf16x8*)(Vh + (size_t)l15 * VT_STR + ks * 32 + g * 8);
      bf16x8 v1 = *(const bf16x8*)(Vh + (size_t)(16 + l15) * VT_STR + ks * 32 + g * 8);
      o0 = MFMA16(af.v, v0, o0);
      o1 = MFMA16(af.v, v1, o1);
    }
#pragma unroll
    for (int r = 0; r < 4; ++r) {
      int orow = mq * 16 + 4 * g + r;
      if (orow < 49) {
        O2[(size_t)orow * 192 + l15]      = (bf)o0[r];
        O2[(size_t)orow * 192 + 16 + l15] = (bf)o1[r];
      }
    }
  }
}

// ---------------- K3: proj GEMM + bias, 1 block = 1 window, inverse roll on store ----------------
__global__ __launch_bounds__(512, 8) void proj_kernel(const float* __restrict__ bout,
                                                      const char* __restrict__ ws,
                                                      float* __restrict__ out) {
  __shared__ __align__(16) bf Ol[49 * O_STRIDE];  // 19600 B

  const bf* woutT = (const bf*)(ws + OFF_WOUTT);
  const bf* O2 = (const bf*)(ws + OFF_O2);

  int bw = blockIdx.x;
  int b = bw >> 6, win = bw & 63;
  int wh = win >> 3, wwi = win & 7;

  int tid = threadIdx.x;
  int wave = tid >> 6, lane = tid & 63;
  int l15 = lane & 15, g = lane >> 4;
  int mrow = wave >> 2, ncol = wave & 3;

  // stage O2 window -> LDS
#pragma unroll
  for (int it = 0; it < 3; ++it) {
    int chunk = it * 512 + tid;
    if (chunk < 1176) {
      int r = chunk / 24, c8 = (chunk % 24) * 8;
      *(bf16x8*)(Ol + r * O_STRIDE + c8) =
          *(const bf16x8*)(O2 + ((size_t)bw * 49 + r) * 192 + c8);
    }
  }
  __syncthreads();

  f32x4 pacc[2][3] = {};
#pragma unroll
  for (int ks = 0; ks < 6; ++ks) {
    int t0 = mrow * 32 + l15;      if (t0 > 48) t0 = 48;
    int t1 = mrow * 32 + 16 + l15; if (t1 > 48) t1 = 48;
    bf16x8 a0 = *(const bf16x8*)(Ol + t0 * O_STRIDE + ks * 32 + g * 8);
    bf16x8 a1 = *(const bf16x8*)(Ol + t1 * O_STRIDE + ks * 32 + g * 8);
#pragma unroll
    for (int nt = 0; nt < 3; ++nt) {
      bf16x8 bfr = *(const bf16x8*)(woutT + (size_t)(ncol * 48 + nt * 16 + l15) * 192 + ks * 32 + g * 8);
      pacc[0][nt] = MFMA16(a0, bfr, pacc[0][nt]);
      pacc[1][nt] = MFMA16(a1, bfr, pacc[1][nt]);
    }
  }
#pragma unroll
  for (int nt = 0; nt < 3; ++nt) {
    int col = ncol * 48 + nt * 16 + l15;
    float bo = bout[col];
#pragma unroll
    for (int mt = 0; mt < 2; ++mt) {
#pragma unroll
      for (int r = 0; r < 4; ++r) {
        int t = mrow * 32 + mt * 16 + 4 * g + r;
        if (t < 49) {
          int tr = t / 7, tc = t % 7;
          int h = wh * 7 + tr + 3; if (h >= 56) h -= 56;
          int w2 = wwi * 7 + tc + 3; if (w2 >= 56) w2 -= 56;
          out[(((size_t)b * 56 + h) * 56 + w2) * 192 + col] = pacc[mt][nt][r] + bo;
        }
      }
    }
  }
}

extern "C" void kernel_launch(void* const* d_in, const int* in_sizes, int n_in,
                              void* d_out, int out_size, void* d_ws, size_t ws_size,
                              hipStream_t stream) {
  const float* x = (const float*)d_in[0];
  const float* wqkv = (const float*)d_in[1];
  const float* wout = (const float*)d_in[2];
  const float* bout = (const float*)d_in[3];
  const float* pos = (const float*)d_in[4];
  char* ws = (char*)d_ws;

  hipLaunchKernelGGL(prep_kernel, dim3(128), dim3(256), 0, stream, wqkv, wout, pos, ws);
  hipLaunchKernelGGL(qkv_kernel, dim3(2048), dim3(512), 0, stream, x, ws);
  hipLaunchKernelGGL(attn_kernel, dim3(12288), dim3(128), 0, stream, (const char*)ws);
  hipLaunchKernelGGL(proj_kernel, dim3(2048), dim3(512), 0, stream, bout, (const char*)ws, (float*)d_out);
}

// Round 9
// 239.039 us; speedup vs baseline: 1.2937x; 1.2937x over previous
//
#include <hip/hip_runtime.h>
#include <hip/hip_bf16.h>

// WindowAttention (Swin) for MI355X, round 9:
//   K0  prep: weight transposes + bf16 bias/mask tables
//   K0b xwin: x (f32, roll fused) -> Xw bf16 [2048][49][192]
//   K_A attn_fused: per (window, head-pair): QKV GEMM (A from global Xw) -> LDS ->
//       swapped-QK^T attention, lane-local softmax, register PV -> O2 [2048][49][192]
//   K_B proj: per window: O2 -> LDS -> GEMM + bias, inverse roll on store -> out
// bf16 MFMA, f32 accum. Fragment layout (gfx950, verified r2-r8):
//   A (16x32): lane l holds A[l&15][8*(l>>4)+j]   B (32x16): lane l holds B[8*(l>>4)+j][l&15]
//   C/D: lane l reg r -> C[4*(l>>4)+r][l&15]
// Attention trick (r6): S^T = K·Q^T with tile T loading K rows
//   kt(T,lane) = 8*(l15>>2) + 4*(T&1) + 32*(T>>1) + (l15&3)
// -> lane (l15,g) holds P[q=l15][kt = g*8 + ...]: softmax = local sum + 2 shfl_xor,
//    and the 4 packed quads are exactly the PV A-frag slices (zero cross-lane traffic).

typedef __bf16 bf16x8 __attribute__((ext_vector_type(8)));
typedef __bf16 bf16x4 __attribute__((ext_vector_type(4)));
typedef float f32x4 __attribute__((ext_vector_type(4)));
using bf = __bf16;

#define MFMA16(a, b, c) __builtin_amdgcn_mfma_f32_16x16x32_bf16((a), (b), (c), 0, 0, 0)

static constexpr float kNEG = -1000000000.0f;
static constexpr float kScale = 0.17677669529663687f;  // 32^-0.5

// workspace layout (bytes)
static constexpr size_t OFF_WQKVT = 0;                      // bf16 [576][192]
static constexpr size_t OFF_WOUTT = 221184;                 // bf16 [192][192]
static constexpr size_t OFF_TBLBF = 294912;                 // bf16 [4][49][68]
static constexpr size_t OFF_XW    = 321568;                 // bf16 [2048][49][192]
static constexpr size_t OFF_O2    = OFF_XW + 38535168ull;   // bf16 [2048][49][192]

static constexpr int QK_STRIDE = 40;   // LDS Q/K row stride (80B rows, 2-way)
static constexpr int VT_STRIDE = 72;   // LDS V^T row stride (144B rows, 2-way)
static constexpr int O_STRIDE  = 200;  // proj LDS stride

// K_A LDS layout (elements are bf16)
static constexpr int Q2_OFF = 0;                    // [2][49][40] = 3920 el, 7840 B
static constexpr int K2_OFF = 7840;                 // [2][49][40]
static constexpr int V2_OFF = 15680;                // [2][32][72] = 4608 el, 9216 B
static constexpr int KA_LDS = 24896;                // bytes -> wave-capped occupancy

__device__ __forceinline__ unsigned pack2(float a, float b) {
  union { bf h[2]; unsigned u; } cv;
  cv.h[0] = (bf)a; cv.h[1] = (bf)b;
  return cv.u;
}

// ---------------- K0: weight transposes + bf16 bias/mask tables ----------------
__global__ void prep_kernel(const float* __restrict__ wqkv, const float* __restrict__ wout,
                            const float* __restrict__ pos, char* __restrict__ ws) {
  bf* wqkvT = (bf*)(ws + OFF_WQKVT);
  bf* woutT = (bf*)(ws + OFF_WOUTT);
  bf* tblbf = (bf*)(ws + OFF_TBLBF);
  int tid = blockIdx.x * blockDim.x + threadIdx.x;
  int nthr = gridDim.x * blockDim.x;
  for (int i = tid; i < 192 * 576; i += nthr) {
    int k = i / 576, n = i % 576;
    wqkvT[n * 192 + k] = (bf)wqkv[i];
  }
  for (int i = tid; i < 192 * 192; i += nthr) {
    int k = i / 192, n = i % 192;
    woutT[n * 192 + k] = (bf)wout[i];
  }
  for (int i = tid; i < 4 * 49 * 68; i += nthr) {
    int type = i / (49 * 68), rem = i % (49 * 68), r = rem / 68, c = rem % 68;
    float v = 0.0f;
    if (c < 64) {
      if (c < 49) {
        int ix = r / 7, iy = r % 7, jx = c / 7, jy = c % 7;
        v = pos[(jx - ix + 6) * 13 + (jy - iy + 6)];
        if ((type & 1) && ((r >= 28) != (c >= 28))) v += kNEG;  // ul mask
        if ((type & 2) && ((iy >= 4) != (jy >= 4))) v += kNEG;  // lr mask
      } else {
        v = kNEG;  // pad cols -> P==0
      }
    }
    tblbf[i] = (bf)v;
  }
}

// ---------------- K0b: x -> rolled window bf16 layout ----------------
__global__ __launch_bounds__(512) void xwin_kernel(const float* __restrict__ x,
                                                   char* __restrict__ ws) {
  bf* Xw = (bf*)(ws + OFF_XW);
  int bw = blockIdx.x;
  int b = bw >> 6, win = bw & 63;
  int wh = win >> 3, wwi = win & 7;
  int tid = threadIdx.x;
#pragma unroll
  for (int it = 0; it < 3; ++it) {
    int chunk = it * 512 + tid;  // 49 rows * 24 chunks of 8
    if (chunk < 1176) {
      int r = chunk / 24, c8 = (chunk % 24) * 8;
      int tr = r / 7, tc = r % 7;
      int h = wh * 7 + tr + 3; if (h >= 56) h -= 56;
      int w = wwi * 7 + tc + 3; if (w >= 56) w -= 56;
      const float* p = x + (((size_t)b * 56 + h) * 56 + w) * 192 + c8;
      bf16x8 v;
#pragma unroll
      for (int j = 0; j < 8; ++j) v[j] = (bf)p[j];
      *(bf16x8*)(Xw + ((size_t)bw * 49 + r) * 192 + c8) = v;
    }
  }
}

// ---------------- K_A: QKV (2 heads) + attention, 1 block = (window, head-pair) ----------------
__global__ __launch_bounds__(512, 4) void attn_fused_kernel(const char* __restrict__ ws,
                                                            char* __restrict__ wsw) {
  __shared__ __align__(16) char smem[KA_LDS];
  bf* Q2 = (bf*)(smem + Q2_OFF);  // [2][49][40]
  bf* K2 = (bf*)(smem + K2_OFF);  // [2][49][40]
  bf* V2 = (bf*)(smem + V2_OFF);  // [2][32][72] (V^T per head: [d][t])

  const bf* wqkvT = (const bf*)(ws + OFF_WQKVT);
  const bf* Xw = (const bf*)(ws + OFF_XW);
  bf* O2 = (bf*)(wsw + OFF_O2);

  int bid = blockIdx.x;
  int bw = bid / 3, hp = bid - bw * 3;          // window, head-pair (heads 2hp, 2hp+1)
  int win = bw & 63;
  int wh = win >> 3, wwi = win & 7;
  int type = ((wh == 7) ? 1 : 0) | ((wwi == 7) ? 2 : 0);
  const bf* Tb = (const bf*)(ws + OFF_TBLBF) + type * 49 * 68;

  int tid = threadIdx.x;
  int wave = tid >> 6, lane = tid & 63;
  int l15 = lane & 15, g = lane >> 4;
  int mrow = wave >> 2, ncol = wave & 3;
  const bf* Xrow = Xw + (size_t)bw * 49 * 192;

  // ---- phase 1: K,V columns for this head-pair (128 cols, 32/wave) ----
  {
    f32x4 acc[2][2] = {};
#pragma unroll
    for (int ks = 0; ks < 6; ++ks) {
      bf16x8 a[2];
#pragma unroll
      for (int mt = 0; mt < 2; ++mt) {
        int t = mrow * 32 + mt * 16 + l15; if (t > 48) t = 48;  // dup; masked later
        a[mt] = *(const bf16x8*)(Xrow + (size_t)t * 192 + ks * 32 + g * 8);
      }
#pragma unroll
      for (int nt = 0; nt < 2; ++nt) {
        int lc = ncol * 32 + nt * 16 + l15;              // 0..127 local KV col
        int n = (lc < 64) ? (192 + hp * 64 + lc) : (384 + hp * 64 + (lc - 64));
        bf16x8 bfr = *(const bf16x8*)(wqkvT + (size_t)n * 192 + ks * 32 + g * 8);
#pragma unroll
        for (int mt = 0; mt < 2; ++mt) acc[mt][nt] = MFMA16(a[mt], bfr, acc[mt][nt]);
      }
    }
#pragma unroll
    for (int nt = 0; nt < 2; ++nt) {
      int lc = ncol * 32 + nt * 16 + l15;
      bool isK = (lc < 64);
      int lh = (lc >> 5) & 1;     // local head
      int d = lc & 31;
#pragma unroll
      for (int mt = 0; mt < 2; ++mt) {
#pragma unroll
        for (int r = 0; r < 4; ++r) {
          int t = mrow * 32 + mt * 16 + 4 * g + r;
          bf bv = (bf)acc[mt][nt][r];
          if (isK) { if (t < 49) K2[(lh * 49 + t) * QK_STRIDE + d] = bv; }
          else     { if (t < 64) V2[(lh * 32 + d) * VT_STRIDE + t] = bv; }  // t>=49 dup, P==0 kills
        }
      }
    }
  }

  // ---- phase 2: Q columns (64 cols, 16/wave) ----
  {
    f32x4 qacc[2] = {};
#pragma unroll
    for (int ks = 0; ks < 6; ++ks) {
      bf16x8 a[2];
#pragma unroll
      for (int mt = 0; mt < 2; ++mt) {
        int t = mrow * 32 + mt * 16 + l15; if (t > 48) t = 48;
        a[mt] = *(const bf16x8*)(Xrow + (size_t)t * 192 + ks * 32 + g * 8);
      }
      int lc = ncol * 16 + l15;
      int n = hp * 64 + lc;
      bf16x8 bfr = *(const bf16x8*)(wqkvT + (size_t)n * 192 + ks * 32 + g * 8);
      qacc[0] = MFMA16(a[0], bfr, qacc[0]);
      qacc[1] = MFMA16(a[1], bfr, qacc[1]);
    }
    int lc = ncol * 16 + l15;
    int lh = lc >> 5, d = lc & 31;
#pragma unroll
    for (int mt = 0; mt < 2; ++mt) {
#pragma unroll
      for (int r = 0; r < 4; ++r) {
        int t = mrow * 32 + mt * 16 + 4 * g + r;
        if (t < 49) Q2[(lh * 49 + t) * QK_STRIDE + d] = (bf)qacc[mt][r];
      }
    }
  }
  __syncthreads();

  // ---- phase 3: attention, exactly 1 item per wave: (local head, q-tile) ----
  int h2 = wave >> 2, mq = wave & 3;
  const bf* Qh = Q2 + h2 * 49 * QK_STRIDE;
  const bf* Kh = K2 + h2 * 49 * QK_STRIDE;
  const bf* Vh = V2 + h2 * 32 * VT_STRIDE;

  int q = mq * 16 + l15;
  int qc = q > 48 ? 48 : q;  // dup; rows q>=49 discarded on store
  bf16x8 qf = *(const bf16x8*)(Qh + qc * QK_STRIDE + g * 8);  // B-frag Q[q][d]

  f32x4 sa[4];
#pragma unroll
  for (int T = 0; T < 4; ++T) {
    int kt = ((l15 >> 2) << 3) + ((T & 1) << 2) + ((T >> 1) << 5) + (l15 & 3);
    int ktc = kt > 48 ? 48 : kt;  // dup; killed by NEG bias col
    bf16x8 kf = *(const bf16x8*)(Kh + ktc * QK_STRIDE + g * 8);  // A-frag K[kt][d]
    f32x4 z = {};
    sa[T] = MFMA16(kf, qf, z);
  }

  // scale + bias + exp (no max-subtract; masked cols -> exp(-1e9)=0)
  float e[4][4];
  float lsum = 0.0f;
#pragma unroll
  for (int T = 0; T < 4; ++T) {
    int cb = (g << 3) + ((T & 1) << 2) + ((T >> 1) << 5);
    bf16x4 bias = *(const bf16x4*)(Tb + qc * 68 + cb);
#pragma unroll
    for (int r = 0; r < 4; ++r) {
      float ev = __expf(sa[T][r] * kScale + (float)bias[r]);
      e[T][r] = ev;
      lsum += ev;
    }
  }
  lsum += __shfl_xor(lsum, 16);
  lsum += __shfl_xor(lsum, 32);
  float rinv = 1.0f / lsum;
  unsigned pp[4][2];
#pragma unroll
  for (int T = 0; T < 4; ++T) {
    pp[T][0] = pack2(e[T][0] * rinv, e[T][1] * rinv);
    pp[T][1] = pack2(e[T][2] * rinv, e[T][3] * rinv);
  }

  // O = P V : A-frags from pp regs, B-frags from LDS V^T
  f32x4 o0 = {}, o1 = {};
#pragma unroll
  for (int ks = 0; ks < 2; ++ks) {
    union { unsigned u[4]; bf16x8 v; } af;
    af.u[0] = pp[2 * ks][0];
    af.u[1] = pp[2 * ks][1];
    af.u[2] = pp[2 * ks + 1][0];
    af.u[3] = pp[2 * ks + 1][1];
    bf16x8 v0 = *(const bf16x8*)(Vh + l15 * VT_STRIDE + ks * 32 + g * 8);
    bf16x8 v1 = *(const bf16x8*)(Vh + (16 + l15) * VT_STRIDE + ks * 32 + g * 8);
    o0 = MFMA16(af.v, v0, o0);
    o1 = MFMA16(af.v, v1, o1);
  }
  int hcol = (hp * 2 + h2) * 32;
#pragma unroll
  for (int r = 0; r < 4; ++r) {
    int orow = mq * 16 + 4 * g + r;
    if (orow < 49) {
      bf* dst = O2 + ((size_t)bw * 49 + orow) * 192 + hcol;
      dst[l15]      = (bf)o0[r];
      dst[16 + l15] = (bf)o1[r];
    }
  }
}

// ---------------- K_B: proj GEMM + bias, 1 block = 1 window, inverse roll on store ----------------
__global__ __launch_bounds__(512, 4) void proj_kernel(const float* __restrict__ bout,
                                                      const char* __restrict__ ws,
                                                      float* __restrict__ out) {
  __shared__ __align__(16) bf Ol[49 * O_STRIDE];  // 19600 B

  const bf* woutT = (const bf*)(ws + OFF_WOUTT);
  const bf* O2 = (const bf*)(ws + OFF_O2);

  int bw = blockIdx.x;
  int b = bw >> 6, win = bw & 63;
  int wh = win >> 3, wwi = win & 7;

  int tid = threadIdx.x;
  int wave = tid >> 6, lane = tid & 63;
  int l15 = lane & 15, g = lane >> 4;
  int mrow = wave >> 2, ncol = wave & 3;

  // stage O2 window -> LDS
#pragma unroll
  for (int it = 0; it < 3; ++it) {
    int chunk = it * 512 + tid;
    if (chunk < 1176) {
      int r = chunk / 24, c8 = (chunk % 24) * 8;
      *(bf16x8*)(Ol + r * O_STRIDE + c8) =
          *(const bf16x8*)(O2 + ((size_t)bw * 49 + r) * 192 + c8);
    }
  }
  __syncthreads();

  f32x4 pacc[2][3] = {};
#pragma unroll
  for (int ks = 0; ks < 6; ++ks) {
    int t0 = mrow * 32 + l15;      if (t0 > 48) t0 = 48;
    int t1 = mrow * 32 + 16 + l15; if (t1 > 48) t1 = 48;
    bf16x8 a0 = *(const bf16x8*)(Ol + t0 * O_STRIDE + ks * 32 + g * 8);
    bf16x8 a1 = *(const bf16x8*)(Ol + t1 * O_STRIDE + ks * 32 + g * 8);
#pragma unroll
    for (int nt = 0; nt < 3; ++nt) {
      bf16x8 bfr = *(const bf16x8*)(woutT + (size_t)(ncol * 48 + nt * 16 + l15) * 192 + ks * 32 + g * 8);
      pacc[0][nt] = MFMA16(a0, bfr, pacc[0][nt]);
      pacc[1][nt] = MFMA16(a1, bfr, pacc[1][nt]);
    }
  }
#pragma unroll
  for (int nt = 0; nt < 3; ++nt) {
    int col = ncol * 48 + nt * 16 + l15;
    float bo = bout[col];
#pragma unroll
    for (int mt = 0; mt < 2; ++mt) {
#pragma unroll
      for (int r = 0; r < 4; ++r) {
        int t = mrow * 32 + mt * 16 + 4 * g + r;
        if (t < 49) {
          int tr = t / 7, tc = t % 7;
          int h = wh * 7 + tr + 3; if (h >= 56) h -= 56;
          int w2 = wwi * 7 + tc + 3; if (w2 >= 56) w2 -= 56;
          out[(((size_t)b * 56 + h) * 56 + w2) * 192 + col] = pacc[mt][nt][r] + bo;
        }
      }
    }
  }
}

extern "C" void kernel_launch(void* const* d_in, const int* in_sizes, int n_in,
                              void* d_out, int out_size, void* d_ws, size_t ws_size,
                              hipStream_t stream) {
  const float* x = (const float*)d_in[0];
  const float* wqkv = (const float*)d_in[1];
  const float* wout = (const float*)d_in[2];
  const float* bout = (const float*)d_in[3];
  const float* pos = (const float*)d_in[4];
  char* ws = (char*)d_ws;

  hipLaunchKernelGGL(prep_kernel, dim3(128), dim3(256), 0, stream, wqkv, wout, pos, ws);
  hipLaunchKernelGGL(xwin_kernel, dim3(2048), dim3(512), 0, stream, x, ws);
  hipLaunchKernelGGL(attn_fused_kernel, dim3(6144), dim3(512), 0, stream, (const char*)ws, ws);
  hipLaunchKernelGGL(proj_kernel, dim3(2048), dim3(512), 0, stream, bout, (const char*)ws, (float*)d_out);
}